// Round 4
// baseline (1534.312 us; speedup 1.0000x reference)
//
#include <hip/hip_runtime.h>

typedef unsigned short u16;
typedef __attribute__((ext_vector_type(4))) float f32x4;
typedef __attribute__((ext_vector_type(8))) short short8;
typedef __attribute__((ext_vector_type(8))) __bf16 bf16x8;

__device__ __forceinline__ float bf2f(u16 h) {
  union { unsigned int u; float f; } c;
  c.u = ((unsigned int)h) << 16;
  return c.f;
}
__device__ __forceinline__ u16 f2bf(float f) {
  union { float f; unsigned int u; } c;
  c.f = f;
  unsigned int u = c.u;
  return (u16)((u + 0x7fffu + ((u >> 16) & 1u)) >> 16);  // RNE
}

// --- async global->LDS, 16B per lane; LDS dst is wave-uniform base + lane*16
typedef __attribute__((address_space(1))) const unsigned int gu32_t;
typedef __attribute__((address_space(3))) unsigned int lu32_t;
__device__ __forceinline__ void gload_lds16(const void* g, void* l) {
  __builtin_amdgcn_global_load_lds((gu32_t*)g, (lu32_t*)l, 16, 0, 0);
}

// --- static row permutations (t is row index in window-flattened space) ---
__device__ __forceinline__ int perm_winpart(int t) {
  const int w = t >> 4, p = t & 15;
  const int r = ((w >> 5) << 2) + (p >> 2);
  const int c = ((w & 31) << 2) + (p & 3);
  return (r << 7) + c;  // image raster index
}
__device__ __forceinline__ int perm_shift(int t, int sh) {
  const int w = t >> 4, p = t & 15;
  const int r = (((w >> 5) << 2) + (p >> 2) + sh) & 127;
  const int c = (((w & 31) << 2) + (p & 3) + sh) & 127;
  return ((((r >> 2) << 5) + (c >> 2)) << 4) + (((r & 3) << 2) + (c & 3));
}

// --- weight fp32 (K,N) -> bf16 transposed (N,K) ---
__global__ __launch_bounds__(256) void transpose_to_bf16(
    const float* __restrict__ src, u16* __restrict__ dst, int K, int N) {
  __shared__ __align__(16) float tile[32][33];
  const int tx = threadIdx.x, ty = threadIdx.y;
  const int bn = blockIdx.x * 32, bk = blockIdx.y * 32;
#pragma unroll
  for (int i = 0; i < 32; i += 8)
    tile[ty + i][tx] = src[(size_t)(bk + ty + i) * N + bn + tx];
  __syncthreads();
#pragma unroll
  for (int i = 0; i < 32; i += 8)
    dst[(size_t)(bn + ty + i) * K + bk + tx] = f2bf(tile[tx][ty + i]);
}

// --- LayerNorm over 512 with fused row gather; one wave per row ---
template <int MODE>  // 1 = winpart, 2 = shift +2
__global__ __launch_bounds__(64) void ln_gather_kernel(
    const float* __restrict__ src, const float* __restrict__ gam,
    const float* __restrict__ bet, u16* __restrict__ out) {
  const int t = blockIdx.x, lane = threadIdx.x;
  const int s = (MODE == 1) ? perm_winpart(t) : perm_shift(t, 2);
  const float* row = src + (size_t)s * 512 + lane * 8;
  f32x4 v0 = *(const f32x4*)(row);
  f32x4 v1 = *(const f32x4*)(row + 4);
  float sum = v0[0] + v0[1] + v0[2] + v0[3] + v1[0] + v1[1] + v1[2] + v1[3];
#pragma unroll
  for (int o = 32; o; o >>= 1) sum += __shfl_xor(sum, o);
  const float m = sum * (1.f / 512.f);
  float vs = 0.f;
#pragma unroll
  for (int i = 0; i < 4; ++i) {
    float d0 = v0[i] - m, d1 = v1[i] - m;
    vs += d0 * d0 + d1 * d1;
  }
#pragma unroll
  for (int o = 32; o; o >>= 1) vs += __shfl_xor(vs, o);
  const float inv = rsqrtf(vs * (1.f / 512.f) + 1e-5f);
  const int cb = lane * 8;
  u16* orow = out + (size_t)t * 512 + cb;
#pragma unroll
  for (int i = 0; i < 4; ++i) {
    orow[i] = f2bf((v0[i] - m) * inv * gam[cb + i] + bet[cb + i]);
    orow[i + 4] = f2bf((v1[i] - m) * inv * gam[cb + i + 4] + bet[cb + i + 4]);
  }
}

// --- res = base[t] + addbf[gather(t)]; then LN(res). Writes both. ---
template <int GM>  // 0 = identity gather, 1 = shift -2 on addbf
__global__ __launch_bounds__(64) void resadd_ln_kernel(
    const float* __restrict__ base, const u16* __restrict__ addbf,
    const float* __restrict__ gam, const float* __restrict__ bet,
    float* __restrict__ resout, u16* __restrict__ lnout) {
  const int t = blockIdx.x, lane = threadIdx.x;
  const int s = (GM == 0) ? t : perm_shift(t, 126);  // 126 == -2 mod 128
  const float* brow = base + (size_t)t * 512 + lane * 8;
  const u16* arow = addbf + (size_t)s * 512 + lane * 8;
  f32x4 b0 = *(const f32x4*)(brow);
  f32x4 b1 = *(const f32x4*)(brow + 4);
  short8 a8 = *(const short8*)(arow);
  float v[8];
#pragma unroll
  for (int i = 0; i < 4; ++i) {
    v[i] = b0[i] + bf2f((u16)a8[i]);
    v[i + 4] = b1[i] + bf2f((u16)a8[i + 4]);
  }
  float sum = 0.f;
#pragma unroll
  for (int i = 0; i < 8; ++i) sum += v[i];
#pragma unroll
  for (int o = 32; o; o >>= 1) sum += __shfl_xor(sum, o);
  const float m = sum * (1.f / 512.f);
  float vs = 0.f;
#pragma unroll
  for (int i = 0; i < 8; ++i) {
    float d = v[i] - m;
    vs += d * d;
  }
#pragma unroll
  for (int o = 32; o; o >>= 1) vs += __shfl_xor(vs, o);
  const float inv = rsqrtf(vs * (1.f / 512.f) + 1e-5f);
  const int cb = lane * 8;
  float* rrow = resout + (size_t)t * 512 + cb;
  f32x4 r0 = {v[0], v[1], v[2], v[3]};
  f32x4 r1 = {v[4], v[5], v[6], v[7]};
  *(f32x4*)(rrow) = r0;
  *(f32x4*)(rrow + 4) = r1;
  u16* orow = lnout + (size_t)t * 512 + cb;
#pragma unroll
  for (int i = 0; i < 8; ++i)
    orow[i] = f2bf((v[i] - m) * inv * gam[cb + i] + bet[cb + i]);
}

// --- per-(window,head) attention: 16 tokens, hd=64; one wave per block ---
// mask (1-valid)*(-1e-9) is numerically negligible (1e-9 << bf16 eps) -> skipped
__global__ __launch_bounds__(64) void attn_kernel(const u16* __restrict__ QKV,
                                                  u16* __restrict__ ATT) {
  __shared__ __align__(16) u16 Qs[16 * 64];
  __shared__ __align__(16) u16 Ks[16 * 64];
  __shared__ __align__(16) u16 Vs[16 * 64];
  __shared__ __align__(16) float Ps[16 * 16];
  const int w = blockIdx.x >> 3, h = blockIdx.x & 7;
  const int lane = threadIdx.x;
  const int p = lane >> 2, q4 = lane & 3;
  const size_t gbase = (size_t)(w * 16 + p) * 1536 + h * 64 + q4 * 16;
  const int lbase = p * 64 + q4 * 16;
  *(short8*)(Qs + lbase) = *(const short8*)(QKV + gbase);
  *(short8*)(Qs + lbase + 8) = *(const short8*)(QKV + gbase + 8);
  *(short8*)(Ks + lbase) = *(const short8*)(QKV + gbase + 512);
  *(short8*)(Ks + lbase + 8) = *(const short8*)(QKV + gbase + 520);
  *(short8*)(Vs + lbase) = *(const short8*)(QKV + gbase + 1024);
  *(short8*)(Vs + lbase + 8) = *(const short8*)(QKV + gbase + 1032);
  __syncthreads();
  // scores: lane owns query p, keys q4*4..q4*4+3
  float sc[4] = {0.f, 0.f, 0.f, 0.f};
  for (int d = 0; d < 64; ++d) {
    const float qv = bf2f(Qs[p * 64 + d]);
#pragma unroll
    for (int j = 0; j < 4; ++j) sc[j] += qv * bf2f(Ks[(q4 * 4 + j) * 64 + d]);
  }
#pragma unroll
  for (int j = 0; j < 4; ++j) sc[j] *= 0.125f;  // 1/sqrt(64)
  float mx = fmaxf(fmaxf(sc[0], sc[1]), fmaxf(sc[2], sc[3]));
  mx = fmaxf(mx, __shfl_xor(mx, 1));
  mx = fmaxf(mx, __shfl_xor(mx, 2));
  float e[4], sm = 0.f;
#pragma unroll
  for (int j = 0; j < 4; ++j) {
    e[j] = expf(sc[j] - mx);
    sm += e[j];
  }
  sm += __shfl_xor(sm, 1);
  sm += __shfl_xor(sm, 2);
  const float isv = 1.f / sm;
#pragma unroll
  for (int j = 0; j < 4; ++j) Ps[p * 16 + q4 * 4 + j] = e[j] * isv;
  __syncthreads();
  // PV: lane owns query p, dims q4*16..q4*16+15
  float o[16];
#pragma unroll
  for (int i = 0; i < 16; ++i) o[i] = 0.f;
  for (int k = 0; k < 16; ++k) {
    const float pk = Ps[p * 16 + k];
#pragma unroll
    for (int dd = 0; dd < 16; ++dd) o[dd] += pk * bf2f(Vs[k * 64 + q4 * 16 + dd]);
  }
  u16* orow = ATT + (size_t)(w * 16 + p) * 512 + h * 64 + q4 * 16;
#pragma unroll
  for (int dd = 0; dd < 16; ++dd) orow[dd] = f2bf(o[dd]);
}

// --- bf16 GEMM: C[M,N] = A[M,K] @ BT[N,K]^T + bias (global_load_lds staging)
// LDS bank-conflict fix (T2, rule #21): involution swizzle slot ^= (row>>1)&3,
// applied on BOTH the global source (staging) and the ds_read offset.
// EPI: 0 = bf16 store; 1 = fp32 store (+ residual if res!=nullptr)
template <int EPI>
__global__ __launch_bounds__(256, 6) void gemm_bf16(
    const u16* __restrict__ A, const u16* __restrict__ BT,
    const float* __restrict__ bias, const float* __restrict__ res,
    void* __restrict__ outp, int M, int N, int K) {
  __shared__ __align__(16) u16 As[128 * 32];
  __shared__ __align__(16) u16 Bs[128 * 32];
  const int tid = threadIdx.x;
  const int wave = tid >> 6;
  const int lane = tid & 63;
  const int bm0 = blockIdx.x * 128;
  const int bn0 = blockIdx.y * 128;
  const int wm = (wave >> 1) * 64;
  const int wn = (wave & 1) * 64;

  const f32x4 zero = {0.f, 0.f, 0.f, 0.f};
  f32x4 acc[4][4];
#pragma unroll
  for (int i = 0; i < 4; ++i)
#pragma unroll
    for (int j = 0; j < 4; ++j) acc[i][j] = zero;

  const int fr = lane & 15;
  const int fk = (lane >> 4) * 8;  // element offset of this lane's 16B k-slot

  for (int k0 = 0; k0 < K; k0 += 32) {
#pragma unroll
    for (int j = 0; j < 2; ++j) {
      const int ebase = j * 256 + wave * 64;  // wave-uniform chunk base
      const int e = ebase + lane;
      const int row = e >> 2;  // 0..127
      // inverse-swizzled global k-slot so linear LDS holds swizzled layout:
      const int kk = (((e & 3) ^ ((e >> 3) & 3)) << 3);
      gload_lds16(A + (size_t)(bm0 + row) * K + k0 + kk, As + ebase * 8);
      gload_lds16(BT + (size_t)(bn0 + row) * K + k0 + kk, Bs + ebase * 8);
    }
    __syncthreads();  // drains vmcnt before barrier
    bf16x8 af[4], bfv[4];
#pragma unroll
    for (int i = 0; i < 4; ++i) {
      const int ro = wm + i * 16 + fr;
      af[i] = *(const bf16x8*)(As + ro * 32 + (fk ^ ((((ro >> 1) & 3)) << 3)));
    }
#pragma unroll
    for (int i = 0; i < 4; ++i) {
      const int rn = wn + i * 16 + fr;
      bfv[i] = *(const bf16x8*)(Bs + rn * 32 + (fk ^ ((((rn >> 1) & 3)) << 3)));
    }
#pragma unroll
    for (int mi = 0; mi < 4; ++mi)
#pragma unroll
      for (int ni = 0; ni < 4; ++ni)
        acc[mi][ni] = __builtin_amdgcn_mfma_f32_16x16x32_bf16(
            af[mi], bfv[ni], acc[mi][ni], 0, 0, 0);
    __syncthreads();
  }

  const int cr = (lane >> 4) * 4;  // C row base: (lane>>4)*4 + reg
  const int cc = lane & 15;        // C col: lane&15
#pragma unroll
  for (int mi = 0; mi < 4; ++mi) {
#pragma unroll
    for (int ni = 0; ni < 4; ++ni) {
      const int cg = bn0 + wn + ni * 16 + cc;
      const float bv2 = bias[cg];
#pragma unroll
      for (int r = 0; r < 4; ++r) {
        const int rg = bm0 + wm + mi * 16 + cr + r;
        float v = acc[mi][ni][r] + bv2;
        if (EPI == 1) {
          if (res) v += res[(size_t)rg * N + cg];
          ((float*)outp)[(size_t)rg * N + cg] = v;
        } else {
          ((u16*)outp)[(size_t)rg * N + cg] = f2bf(v);
        }
      }
    }
  }
}

extern "C" void kernel_launch(void* const* d_in, const int* in_sizes, int n_in,
                              void* d_out, int out_size, void* d_ws,
                              size_t ws_size, hipStream_t stream) {
  (void)in_sizes;
  (void)n_in;
  (void)out_size;
  (void)ws_size;
  const float* x = (const float*)d_in[0];
  const float* ln1_g = (const float*)d_in[1];
  const float* ln1_b = (const float*)d_in[2];
  const float* ln2_g = (const float*)d_in[3];
  const float* ln2_b = (const float*)d_in[4];
  const float* ln3_g = (const float*)d_in[5];
  const float* ln3_b = (const float*)d_in[6];
  const float* ln4_g = (const float*)d_in[7];
  const float* ln4_b = (const float*)d_in[8];
  const float* qkv1_w = (const float*)d_in[9];
  const float* qkv1_b = (const float*)d_in[10];
  const float* ao1_w = (const float*)d_in[11];
  const float* ao1_b = (const float*)d_in[12];
  const float* qkv2_w = (const float*)d_in[13];
  const float* qkv2_b = (const float*)d_in[14];
  const float* ao2_w = (const float*)d_in[15];
  const float* ao2_b = (const float*)d_in[16];
  const float* m1a_w = (const float*)d_in[17];
  const float* m1a_b = (const float*)d_in[18];
  const float* m1b_w = (const float*)d_in[19];
  const float* m1b_b = (const float*)d_in[20];
  const float* m2a_w = (const float*)d_in[21];
  const float* m2a_b = (const float*)d_in[22];
  const float* m2b_w = (const float*)d_in[23];
  const float* m2b_b = (const float*)d_in[24];

  char* ws = (char*)d_ws;
  u16* wt = (u16*)ws;  // transposed bf16 weights (N,K), element offsets:
  u16* w_qkv1 = wt;                // 1536x512
  u16* w_ao1 = wt + 786432;        // 512x512
  u16* w_qkv2 = wt + 1048576;      // 1536x512
  u16* w_ao2 = wt + 1835008;       // 512x512
  u16* w_m1a = wt + 2097152;       // 2048x512
  u16* w_m1b = wt + 3145728;       // 512x2048
  u16* w_m2a = wt + 4194304;       // 2048x512
  u16* w_m2b = wt + 5242880;       // 512x2048  (end byte 12582912)
  u16* A1 = (u16*)(ws + 12582912);       // 16384x512 bf16 (LN out; aliased by ATT)
  u16* ATT = A1;                         // attn pre-proj (A1 dead by then)
  u16* A0 = (u16*)(ws + 29360128);       // 16384x512 bf16 (attn proj out)
  u16* BIG = (u16*)(ws + 46137344);      // 16384x2048 bf16 (qkv / mlp hidden)
  float* R1 = (float*)(ws + 113246208);  // 16384x512 f32 (res1 then res2)
  float* O1 = (float*)(ws + 146800640);  // 16384x512 f32 (out1); end 180355072

  const dim3 tb(32, 8);
  transpose_to_bf16<<<dim3(48, 16), tb, 0, stream>>>(qkv1_w, w_qkv1, 512, 1536);
  transpose_to_bf16<<<dim3(16, 16), tb, 0, stream>>>(ao1_w, w_ao1, 512, 512);
  transpose_to_bf16<<<dim3(48, 16), tb, 0, stream>>>(qkv2_w, w_qkv2, 512, 1536);
  transpose_to_bf16<<<dim3(16, 16), tb, 0, stream>>>(ao2_w, w_ao2, 512, 512);
  transpose_to_bf16<<<dim3(64, 16), tb, 0, stream>>>(m1a_w, w_m1a, 512, 2048);
  transpose_to_bf16<<<dim3(16, 64), tb, 0, stream>>>(m1b_w, w_m1b, 2048, 512);
  transpose_to_bf16<<<dim3(64, 16), tb, 0, stream>>>(m2a_w, w_m2a, 512, 2048);
  transpose_to_bf16<<<dim3(16, 64), tb, 0, stream>>>(m2b_w, w_m2b, 2048, 512);

  // ---- branch 1: W-MSA ----
  ln_gather_kernel<1><<<16384, 64, 0, stream>>>(x, ln1_g, ln1_b, A1);
  gemm_bf16<0><<<dim3(128, 12), 256, 0, stream>>>(A1, w_qkv1, qkv1_b, nullptr,
                                                  BIG, 16384, 1536, 512);
  attn_kernel<<<8192, 64, 0, stream>>>(BIG, ATT);
  gemm_bf16<0><<<dim3(128, 4), 256, 0, stream>>>(ATT, w_ao1, ao1_b, nullptr, A0,
                                                 16384, 512, 512);
  resadd_ln_kernel<0><<<16384, 64, 0, stream>>>(x, A0, ln2_g, ln2_b, R1, A1);
  gemm_bf16<0><<<dim3(128, 16), 256, 0, stream>>>(A1, w_m1a, m1a_b, nullptr,
                                                  BIG, 16384, 2048, 512);
  gemm_bf16<1><<<dim3(128, 4), 256, 0, stream>>>(BIG, w_m1b, m1b_b, R1, O1,
                                                 16384, 512, 2048);

  // ---- branch 2: SW-MSA ----
  ln_gather_kernel<2><<<16384, 64, 0, stream>>>(O1, ln3_g, ln3_b, A1);
  gemm_bf16<0><<<dim3(128, 12), 256, 0, stream>>>(A1, w_qkv2, qkv2_b, nullptr,
                                                  BIG, 16384, 1536, 512);
  attn_kernel<<<8192, 64, 0, stream>>>(BIG, ATT);
  gemm_bf16<0><<<dim3(128, 4), 256, 0, stream>>>(ATT, w_ao2, ao2_b, nullptr, A0,
                                                 16384, 512, 512);
  resadd_ln_kernel<1><<<16384, 64, 0, stream>>>(O1, A0, ln4_g, ln4_b, R1, A1);
  gemm_bf16<0><<<dim3(128, 16), 256, 0, stream>>>(A1, w_m2a, m2a_b, nullptr,
                                                  BIG, 16384, 2048, 512);
  gemm_bf16<1><<<dim3(128, 4), 256, 0, stream>>>(BIG, w_m2b, m2b_b, R1,
                                                 (float*)d_out, 16384, 512, 2048);
}

// Round 5
// 553.118 us; speedup vs baseline: 2.7739x; 2.7739x over previous
//
#include <hip/hip_runtime.h>

typedef unsigned short u16;
typedef __attribute__((ext_vector_type(4))) float f32x4;
typedef __attribute__((ext_vector_type(8))) short short8;
typedef __attribute__((ext_vector_type(8))) __bf16 bf16x8;

__device__ __forceinline__ float bf2f(u16 h) {
  union { unsigned int u; float f; } c;
  c.u = ((unsigned int)h) << 16;
  return c.f;
}
__device__ __forceinline__ u16 f2bf(float f) {
  union { float f; unsigned int u; } c;
  c.f = f;
  unsigned int u = c.u;
  return (u16)((u + 0x7fffu + ((u >> 16) & 1u)) >> 16);  // RNE
}

// --- async global->LDS, 16B per lane; LDS dst is wave-uniform base + lane*16
typedef __attribute__((address_space(1))) const unsigned int gu32_t;
typedef __attribute__((address_space(3))) unsigned int lu32_t;
__device__ __forceinline__ void gload_lds16(const void* g, void* l) {
  __builtin_amdgcn_global_load_lds((gu32_t*)g, (lu32_t*)l, 16, 0, 0);
}

// --- static row permutations (t is row index in window-flattened space) ---
__device__ __forceinline__ int perm_winpart(int t) {
  const int w = t >> 4, p = t & 15;
  const int r = ((w >> 5) << 2) + (p >> 2);
  const int c = ((w & 31) << 2) + (p & 3);
  return (r << 7) + c;  // image raster index
}
__device__ __forceinline__ int perm_shift(int t, int sh) {
  const int w = t >> 4, p = t & 15;
  const int r = (((w >> 5) << 2) + (p >> 2) + sh) & 127;
  const int c = (((w & 31) << 2) + (p & 3) + sh) & 127;
  return ((((r >> 2) << 5) + (c >> 2)) << 4) + (((r & 3) << 2) + (c & 3));
}

// --- weight fp32 (K,N) -> bf16 transposed (N,K) ---
__global__ __launch_bounds__(256) void transpose_to_bf16(
    const float* __restrict__ src, u16* __restrict__ dst, int K, int N) {
  __shared__ __align__(16) float tile[32][33];
  const int tx = threadIdx.x, ty = threadIdx.y;
  const int bn = blockIdx.x * 32, bk = blockIdx.y * 32;
#pragma unroll
  for (int i = 0; i < 32; i += 8)
    tile[ty + i][tx] = src[(size_t)(bk + ty + i) * N + bn + tx];
  __syncthreads();
#pragma unroll
  for (int i = 0; i < 32; i += 8)
    dst[(size_t)(bn + ty + i) * K + bk + tx] = f2bf(tile[tx][ty + i]);
}

// --- LayerNorm over 512 with fused row gather; one wave per row ---
template <int MODE>  // 1 = winpart, 2 = shift +2
__global__ __launch_bounds__(64) void ln_gather_kernel(
    const float* __restrict__ src, const float* __restrict__ gam,
    const float* __restrict__ bet, u16* __restrict__ out) {
  const int t = blockIdx.x, lane = threadIdx.x;
  const int s = (MODE == 1) ? perm_winpart(t) : perm_shift(t, 2);
  const float* row = src + (size_t)s * 512 + lane * 8;
  f32x4 v0 = *(const f32x4*)(row);
  f32x4 v1 = *(const f32x4*)(row + 4);
  float sum = v0[0] + v0[1] + v0[2] + v0[3] + v1[0] + v1[1] + v1[2] + v1[3];
#pragma unroll
  for (int o = 32; o; o >>= 1) sum += __shfl_xor(sum, o);
  const float m = sum * (1.f / 512.f);
  float vs = 0.f;
#pragma unroll
  for (int i = 0; i < 4; ++i) {
    float d0 = v0[i] - m, d1 = v1[i] - m;
    vs += d0 * d0 + d1 * d1;
  }
#pragma unroll
  for (int o = 32; o; o >>= 1) vs += __shfl_xor(vs, o);
  const float inv = rsqrtf(vs * (1.f / 512.f) + 1e-5f);
  const int cb = lane * 8;
  u16* orow = out + (size_t)t * 512 + cb;
#pragma unroll
  for (int i = 0; i < 4; ++i) {
    orow[i] = f2bf((v0[i] - m) * inv * gam[cb + i] + bet[cb + i]);
    orow[i + 4] = f2bf((v1[i] - m) * inv * gam[cb + i + 4] + bet[cb + i + 4]);
  }
}

// --- res = base[t] + addbf[gather(t)]; then LN(res). Writes both. ---
template <int GM>  // 0 = identity gather, 1 = shift -2 on addbf
__global__ __launch_bounds__(64) void resadd_ln_kernel(
    const float* __restrict__ base, const u16* __restrict__ addbf,
    const float* __restrict__ gam, const float* __restrict__ bet,
    float* __restrict__ resout, u16* __restrict__ lnout) {
  const int t = blockIdx.x, lane = threadIdx.x;
  const int s = (GM == 0) ? t : perm_shift(t, 126);  // 126 == -2 mod 128
  const float* brow = base + (size_t)t * 512 + lane * 8;
  const u16* arow = addbf + (size_t)s * 512 + lane * 8;
  f32x4 b0 = *(const f32x4*)(brow);
  f32x4 b1 = *(const f32x4*)(brow + 4);
  short8 a8 = *(const short8*)(arow);
  float v[8];
#pragma unroll
  for (int i = 0; i < 4; ++i) {
    v[i] = b0[i] + bf2f((u16)a8[i]);
    v[i + 4] = b1[i] + bf2f((u16)a8[i + 4]);
  }
  float sum = 0.f;
#pragma unroll
  for (int i = 0; i < 8; ++i) sum += v[i];
#pragma unroll
  for (int o = 32; o; o >>= 1) sum += __shfl_xor(sum, o);
  const float m = sum * (1.f / 512.f);
  float vs = 0.f;
#pragma unroll
  for (int i = 0; i < 8; ++i) {
    float d = v[i] - m;
    vs += d * d;
  }
#pragma unroll
  for (int o = 32; o; o >>= 1) vs += __shfl_xor(vs, o);
  const float inv = rsqrtf(vs * (1.f / 512.f) + 1e-5f);
  const int cb = lane * 8;
  float* rrow = resout + (size_t)t * 512 + cb;
  f32x4 r0 = {v[0], v[1], v[2], v[3]};
  f32x4 r1 = {v[4], v[5], v[6], v[7]};
  *(f32x4*)(rrow) = r0;
  *(f32x4*)(rrow + 4) = r1;
  u16* orow = lnout + (size_t)t * 512 + cb;
#pragma unroll
  for (int i = 0; i < 8; ++i)
    orow[i] = f2bf((v[i] - m) * inv * gam[cb + i] + bet[cb + i]);
}

// --- per-(window,head) attention: 16 tokens, hd=64; one wave per block ---
// mask (1-valid)*(-1e-9) is numerically negligible (1e-9 << bf16 eps) -> skipped
__global__ __launch_bounds__(64) void attn_kernel(const u16* __restrict__ QKV,
                                                  u16* __restrict__ ATT) {
  __shared__ __align__(16) u16 Qs[16 * 64];
  __shared__ __align__(16) u16 Ks[16 * 64];
  __shared__ __align__(16) u16 Vs[16 * 64];
  __shared__ __align__(16) float Ps[16 * 16];
  const int w = blockIdx.x >> 3, h = blockIdx.x & 7;
  const int lane = threadIdx.x;
  const int p = lane >> 2, q4 = lane & 3;
  const size_t gbase = (size_t)(w * 16 + p) * 1536 + h * 64 + q4 * 16;
  const int lbase = p * 64 + q4 * 16;
  *(short8*)(Qs + lbase) = *(const short8*)(QKV + gbase);
  *(short8*)(Qs + lbase + 8) = *(const short8*)(QKV + gbase + 8);
  *(short8*)(Ks + lbase) = *(const short8*)(QKV + gbase + 512);
  *(short8*)(Ks + lbase + 8) = *(const short8*)(QKV + gbase + 520);
  *(short8*)(Vs + lbase) = *(const short8*)(QKV + gbase + 1024);
  *(short8*)(Vs + lbase + 8) = *(const short8*)(QKV + gbase + 1032);
  __syncthreads();
  // scores: lane owns query p, keys q4*4..q4*4+3
  float sc[4] = {0.f, 0.f, 0.f, 0.f};
  for (int d = 0; d < 64; ++d) {
    const float qv = bf2f(Qs[p * 64 + d]);
#pragma unroll
    for (int j = 0; j < 4; ++j) sc[j] += qv * bf2f(Ks[(q4 * 4 + j) * 64 + d]);
  }
#pragma unroll
  for (int j = 0; j < 4; ++j) sc[j] *= 0.125f;  // 1/sqrt(64)
  float mx = fmaxf(fmaxf(sc[0], sc[1]), fmaxf(sc[2], sc[3]));
  mx = fmaxf(mx, __shfl_xor(mx, 1));
  mx = fmaxf(mx, __shfl_xor(mx, 2));
  float e[4], sm = 0.f;
#pragma unroll
  for (int j = 0; j < 4; ++j) {
    e[j] = expf(sc[j] - mx);
    sm += e[j];
  }
  sm += __shfl_xor(sm, 1);
  sm += __shfl_xor(sm, 2);
  const float isv = 1.f / sm;
#pragma unroll
  for (int j = 0; j < 4; ++j) Ps[p * 16 + q4 * 4 + j] = e[j] * isv;
  __syncthreads();
  // PV: lane owns query p, dims q4*16..q4*16+15
  float o[16];
#pragma unroll
  for (int i = 0; i < 16; ++i) o[i] = 0.f;
  for (int k = 0; k < 16; ++k) {
    const float pk = Ps[p * 16 + k];
#pragma unroll
    for (int dd = 0; dd < 16; ++dd) o[dd] += pk * bf2f(Vs[k * 64 + q4 * 16 + dd]);
  }
  u16* orow = ATT + (size_t)(w * 16 + p) * 512 + h * 64 + q4 * 16;
#pragma unroll
  for (int dd = 0; dd < 16; ++dd) orow[dd] = f2bf(o[dd]);
}

// --- bf16 GEMM: C[M,N] = A[M,K] @ BT[N,K]^T + bias (global_load_lds staging)
// LDS swizzle (T2, rule #21): involution slot ^= (row>>1)&3 on BOTH the
// global source (staging) and the ds_read offset. Bank conflicts = 0 (R4).
// __launch_bounds__(256,4): 512-reg/SIMD pool / 4 waves = 128 regs >= the
// ~120 (56 VGPR + 64 AGPR acc) this kernel needs -> spill-free (R4 post-mortem:
// (,6) forced an 85-reg budget and spilled acc to scratch, 3.3x regression).
// EPI: 0 = bf16 store; 1 = fp32 store (+ residual if res!=nullptr)
template <int EPI>
__global__ __launch_bounds__(256, 4) void gemm_bf16(
    const u16* __restrict__ A, const u16* __restrict__ BT,
    const float* __restrict__ bias, const float* __restrict__ res,
    void* __restrict__ outp, int M, int N, int K) {
  __shared__ __align__(16) u16 As[128 * 32];
  __shared__ __align__(16) u16 Bs[128 * 32];
  const int tid = threadIdx.x;
  const int wave = tid >> 6;
  const int lane = tid & 63;
  const int bm0 = blockIdx.x * 128;
  const int bn0 = blockIdx.y * 128;
  const int wm = (wave >> 1) * 64;
  const int wn = (wave & 1) * 64;

  const f32x4 zero = {0.f, 0.f, 0.f, 0.f};
  f32x4 acc[4][4];
#pragma unroll
  for (int i = 0; i < 4; ++i)
#pragma unroll
    for (int j = 0; j < 4; ++j) acc[i][j] = zero;

  const int fr = lane & 15;
  const int fk = (lane >> 4) * 8;  // element offset of this lane's 16B k-slot

  for (int k0 = 0; k0 < K; k0 += 32) {
#pragma unroll
    for (int j = 0; j < 2; ++j) {
      const int ebase = j * 256 + wave * 64;  // wave-uniform chunk base
      const int e = ebase + lane;
      const int row = e >> 2;  // 0..127
      // inverse-swizzled global k-slot so linear LDS holds swizzled layout:
      const int kk = (((e & 3) ^ ((e >> 3) & 3)) << 3);
      gload_lds16(A + (size_t)(bm0 + row) * K + k0 + kk, As + ebase * 8);
      gload_lds16(BT + (size_t)(bn0 + row) * K + k0 + kk, Bs + ebase * 8);
    }
    __syncthreads();  // drains vmcnt before barrier
    bf16x8 af[4], bfv[4];
#pragma unroll
    for (int i = 0; i < 4; ++i) {
      const int ro = wm + i * 16 + fr;
      af[i] = *(const bf16x8*)(As + ro * 32 + (fk ^ ((((ro >> 1) & 3)) << 3)));
    }
#pragma unroll
    for (int i = 0; i < 4; ++i) {
      const int rn = wn + i * 16 + fr;
      bfv[i] = *(const bf16x8*)(Bs + rn * 32 + (fk ^ ((((rn >> 1) & 3)) << 3)));
    }
#pragma unroll
    for (int mi = 0; mi < 4; ++mi)
#pragma unroll
      for (int ni = 0; ni < 4; ++ni)
        acc[mi][ni] = __builtin_amdgcn_mfma_f32_16x16x32_bf16(
            af[mi], bfv[ni], acc[mi][ni], 0, 0, 0);
    __syncthreads();
  }

  const int cr = (lane >> 4) * 4;  // C row base: (lane>>4)*4 + reg
  const int cc = lane & 15;        // C col: lane&15
#pragma unroll
  for (int mi = 0; mi < 4; ++mi) {
#pragma unroll
    for (int ni = 0; ni < 4; ++ni) {
      const int cg = bn0 + wn + ni * 16 + cc;
      const float bv2 = bias[cg];
#pragma unroll
      for (int r = 0; r < 4; ++r) {
        const int rg = bm0 + wm + mi * 16 + cr + r;
        float v = acc[mi][ni][r] + bv2;
        if (EPI == 1) {
          if (res) v += res[(size_t)rg * N + cg];
          ((float*)outp)[(size_t)rg * N + cg] = v;
        } else {
          ((u16*)outp)[(size_t)rg * N + cg] = f2bf(v);
        }
      }
    }
  }
}

extern "C" void kernel_launch(void* const* d_in, const int* in_sizes, int n_in,
                              void* d_out, int out_size, void* d_ws,
                              size_t ws_size, hipStream_t stream) {
  (void)in_sizes;
  (void)n_in;
  (void)out_size;
  (void)ws_size;
  const float* x = (const float*)d_in[0];
  const float* ln1_g = (const float*)d_in[1];
  const float* ln1_b = (const float*)d_in[2];
  const float* ln2_g = (const float*)d_in[3];
  const float* ln2_b = (const float*)d_in[4];
  const float* ln3_g = (const float*)d_in[5];
  const float* ln3_b = (const float*)d_in[6];
  const float* ln4_g = (const float*)d_in[7];
  const float* ln4_b = (const float*)d_in[8];
  const float* qkv1_w = (const float*)d_in[9];
  const float* qkv1_b = (const float*)d_in[10];
  const float* ao1_w = (const float*)d_in[11];
  const float* ao1_b = (const float*)d_in[12];
  const float* qkv2_w = (const float*)d_in[13];
  const float* qkv2_b = (const float*)d_in[14];
  const float* ao2_w = (const float*)d_in[15];
  const float* ao2_b = (const float*)d_in[16];
  const float* m1a_w = (const float*)d_in[17];
  const float* m1a_b = (const float*)d_in[18];
  const float* m1b_w = (const float*)d_in[19];
  const float* m1b_b = (const float*)d_in[20];
  const float* m2a_w = (const float*)d_in[21];
  const float* m2a_b = (const float*)d_in[22];
  const float* m2b_w = (const float*)d_in[23];
  const float* m2b_b = (const float*)d_in[24];

  char* ws = (char*)d_ws;
  u16* wt = (u16*)ws;  // transposed bf16 weights (N,K), element offsets:
  u16* w_qkv1 = wt;                // 1536x512
  u16* w_ao1 = wt + 786432;        // 512x512
  u16* w_qkv2 = wt + 1048576;      // 1536x512
  u16* w_ao2 = wt + 1835008;       // 512x512
  u16* w_m1a = wt + 2097152;       // 2048x512
  u16* w_m1b = wt + 3145728;       // 512x2048
  u16* w_m2a = wt + 4194304;       // 2048x512
  u16* w_m2b = wt + 5242880;       // 512x2048  (end byte 12582912)
  u16* A1 = (u16*)(ws + 12582912);       // 16384x512 bf16 (LN out; aliased by ATT)
  u16* ATT = A1;                         // attn pre-proj (A1 dead by then)
  u16* A0 = (u16*)(ws + 29360128);       // 16384x512 bf16 (attn proj out)
  u16* BIG = (u16*)(ws + 46137344);      // 16384x2048 bf16 (qkv / mlp hidden)
  float* R1 = (float*)(ws + 113246208);  // 16384x512 f32 (res1 then res2)
  float* O1 = (float*)(ws + 146800640);  // 16384x512 f32 (out1); end 180355072

  const dim3 tb(32, 8);
  transpose_to_bf16<<<dim3(48, 16), tb, 0, stream>>>(qkv1_w, w_qkv1, 512, 1536);
  transpose_to_bf16<<<dim3(16, 16), tb, 0, stream>>>(ao1_w, w_ao1, 512, 512);
  transpose_to_bf16<<<dim3(48, 16), tb, 0, stream>>>(qkv2_w, w_qkv2, 512, 1536);
  transpose_to_bf16<<<dim3(16, 16), tb, 0, stream>>>(ao2_w, w_ao2, 512, 512);
  transpose_to_bf16<<<dim3(64, 16), tb, 0, stream>>>(m1a_w, w_m1a, 512, 2048);
  transpose_to_bf16<<<dim3(16, 64), tb, 0, stream>>>(m1b_w, w_m1b, 2048, 512);
  transpose_to_bf16<<<dim3(64, 16), tb, 0, stream>>>(m2a_w, w_m2a, 512, 2048);
  transpose_to_bf16<<<dim3(16, 64), tb, 0, stream>>>(m2b_w, w_m2b, 2048, 512);

  // ---- branch 1: W-MSA ----
  ln_gather_kernel<1><<<16384, 64, 0, stream>>>(x, ln1_g, ln1_b, A1);
  gemm_bf16<0><<<dim3(128, 12), 256, 0, stream>>>(A1, w_qkv1, qkv1_b, nullptr,
                                                  BIG, 16384, 1536, 512);
  attn_kernel<<<8192, 64, 0, stream>>>(BIG, ATT);
  gemm_bf16<0><<<dim3(128, 4), 256, 0, stream>>>(ATT, w_ao1, ao1_b, nullptr, A0,
                                                 16384, 512, 512);
  resadd_ln_kernel<0><<<16384, 64, 0, stream>>>(x, A0, ln2_g, ln2_b, R1, A1);
  gemm_bf16<0><<<dim3(128, 16), 256, 0, stream>>>(A1, w_m1a, m1a_b, nullptr,
                                                  BIG, 16384, 2048, 512);
  gemm_bf16<1><<<dim3(128, 4), 256, 0, stream>>>(BIG, w_m1b, m1b_b, R1, O1,
                                                 16384, 512, 2048);

  // ---- branch 2: SW-MSA ----
  ln_gather_kernel<2><<<16384, 64, 0, stream>>>(O1, ln3_g, ln3_b, A1);
  gemm_bf16<0><<<dim3(128, 12), 256, 0, stream>>>(A1, w_qkv2, qkv2_b, nullptr,
                                                  BIG, 16384, 1536, 512);
  attn_kernel<<<8192, 64, 0, stream>>>(BIG, ATT);
  gemm_bf16<0><<<dim3(128, 4), 256, 0, stream>>>(ATT, w_ao2, ao2_b, nullptr, A0,
                                                 16384, 512, 512);
  resadd_ln_kernel<1><<<16384, 64, 0, stream>>>(O1, A0, ln4_g, ln4_b, R1, A1);
  gemm_bf16<0><<<dim3(128, 16), 256, 0, stream>>>(A1, w_m2a, m2a_b, nullptr,
                                                  BIG, 16384, 2048, 512);
  gemm_bf16<1><<<dim3(128, 4), 256, 0, stream>>>(BIG, w_m2b, m2b_b, R1,
                                                 (float*)d_out, 16384, 512, 2048);
}